// Round 1
// baseline (201.916 us; speedup 1.0000x reference)
//
#include <hip/hip_runtime.h>
#include <stdint.h>

#define D_MODEL 1024
#define SEQ     2048
#define BATCH   2
#define NHEADS  16
#define HDIM    64
#define ROWS    (BATCH*SEQ)   // 4096

typedef __attribute__((ext_vector_type(8))) short short8;
typedef __attribute__((ext_vector_type(4))) float f32x4;
typedef __attribute__((ext_vector_type(4))) short short4v;

__device__ __forceinline__ unsigned short f2bf(float f){
  union { float f; unsigned int u; } v; v.f = f;
  unsigned int r = v.u + 0x7fffu + ((v.u >> 16) & 1u);   // RNE
  return (unsigned short)(r >> 16);
}

__device__ __forceinline__ void gload16(const void* g, void* l){
  __builtin_amdgcn_global_load_lds((__attribute__((address_space(1))) void*)(uintptr_t)g,
                                   (__attribute__((address_space(3))) void*)l, 16, 0, 0);
}

// ---------------- kernel 1: x fp32 -> bf16 ----------------
__global__ __launch_bounds__(256) void cvt_x(const float* __restrict__ x,
                                             unsigned short* __restrict__ xb){
  const int i = blockIdx.x*256 + threadIdx.x;     // one float4 per thread
  float4 v = ((const float4*)x)[i];
  short4v o;
  o[0] = (short)f2bf(v.x); o[1] = (short)f2bf(v.y);
  o[2] = (short)f2bf(v.z); o[3] = (short)f2bf(v.w);
  ((short4v*)xb)[i] = o;
}

// ---------------- kernel 2: W [k][n] fp32 -> Wt [n][k] bf16 (x3) ----------------
__global__ __launch_bounds__(256) void wtrans(const float* __restrict__ Wq,
                                              const float* __restrict__ Wk,
                                              const float* __restrict__ Wv,
                                              unsigned short* __restrict__ Wt){
  const float* W = (blockIdx.z==0)?Wq:((blockIdx.z==1)?Wk:Wv);
  unsigned short* dst = Wt + (size_t)blockIdx.z*1048576;
  __shared__ float tile[32][33];
  const int tx = threadIdx.x & 31, ty = threadIdx.x >> 5;   // 32 x 8
  const int n0 = blockIdx.x*32, k0 = blockIdx.y*32;
  #pragma unroll
  for (int j=0;j<32;j+=8)
    tile[ty+j][tx] = W[(size_t)(k0+ty+j)*D_MODEL + n0+tx];
  __syncthreads();
  #pragma unroll
  for (int j=0;j<32;j+=8)
    dst[(size_t)(n0+ty+j)*D_MODEL + k0+tx] = f2bf(tile[tx][ty+j]);
}

// ---------------- kernel 3: QKV GEMM (bf16 MFMA, 128x128 tile, BK=32) ----------------
__global__ __launch_bounds__(256) void qkv_gemm(
    const unsigned short* __restrict__ xb, const unsigned short* __restrict__ wtb,
    const float* __restrict__ bq, const float* __restrict__ bk, const float* __restrict__ bv,
    unsigned short* __restrict__ qb, unsigned short* __restrict__ kbuf,
    unsigned short* __restrict__ vbuf)
{
  __shared__ unsigned short As[128*32];
  __shared__ unsigned short Bs[128*32];
  const int mat = blockIdx.z;
  const unsigned short* wt = wtb + (size_t)mat*1048576;
  const float* bias = (mat==0)?bq:((mat==1)?bk:bv);
  unsigned short* outp = (mat==0)?qb:((mat==1)?kbuf:vbuf);
  const int bm = blockIdx.x, bn = blockIdx.y;
  const int t = threadIdx.x, w = t>>6, lane = t&63;
  const int g = lane>>4, l15 = lane&15;
  const int wm = w>>1, wn = w&1;

  const int srow = (w<<5) + (lane>>2);     // staging row (j=0); +16 for j=1
  const int scol = (lane&3)*8;

  f32x4 acc[4][4];
  #pragma unroll
  for (int i=0;i<4;++i)
    #pragma unroll
    for (int j=0;j<4;++j) acc[i][j] = (f32x4){0.f,0.f,0.f,0.f};

  for (int kt=0; kt<32; ++kt){
    const int k0 = kt*32;
    #pragma unroll
    for (int j=0;j<2;++j){
      gload16(xb + (size_t)(bm*128 + srow + j*16)*D_MODEL + k0 + scol, &As[(w<<10)+(j<<9)]);
      gload16(wt + (size_t)(bn*128 + srow + j*16)*D_MODEL + k0 + scol, &Bs[(w<<10)+(j<<9)]);
    }
    __syncthreads();
    short8 a[4], b[4];
    #pragma unroll
    for (int mr=0;mr<4;++mr) a[mr] = *(const short8*)&As[(wm*64 + mr*16 + l15)*32 + g*8];
    #pragma unroll
    for (int nr=0;nr<4;++nr) b[nr] = *(const short8*)&Bs[(wn*64 + nr*16 + l15)*32 + g*8];
    #pragma unroll
    for (int mr=0;mr<4;++mr)
      #pragma unroll
      for (int nr=0;nr<4;++nr)
        acc[mr][nr] = __builtin_amdgcn_mfma_f32_16x16x32_bf16(a[mr], b[nr], acc[mr][nr], 0,0,0);
    __syncthreads();
  }
  // epilogue: +bias, ->bf16, scatter into [B*H][S][64]
  #pragma unroll
  for (int mr=0;mr<4;++mr){
    const int rowb = bm*128 + wm*64 + mr*16 + g*4;
    #pragma unroll
    for (int nr=0;nr<4;++nr){
      const int col = bn*128 + wn*64 + nr*16 + l15;
      const float bsv = bias[col];
      const int h = col>>6, d = col&63;
      #pragma unroll
      for (int r=0;r<4;++r){
        const int m = rowb + r;
        const int b_ = m>>11, s = m&2047;
        outp[(((size_t)(b_*NHEADS + h))*SEQ + s)*HDIM + d] = f2bf(acc[mr][nr][r] + bsv);
      }
    }
  }
}

// ---------------- kernel 4: flash attention (per (bh, 64 q-rows)) ----------------
__global__ __launch_bounds__(256) void attn_fwd(
  const unsigned short* __restrict__ Qb, const unsigned short* __restrict__ Kb,
  const unsigned short* __restrict__ Vb, float* __restrict__ ctx)
{
  __shared__ unsigned short Vt[64*72];       // V^T tile [d][k], padded stride 72
  __shared__ unsigned short Pl[4][16*72];    // per-wave P tile [16][64], padded
  const int bh = blockIdx.y;
  const int q0 = blockIdx.x*64;
  const int t = threadIdx.x, w = t>>6, lane = t&63, g = lane>>4, l15 = lane&15;
  const size_t hbase = (size_t)bh*SEQ*HDIM;
  const unsigned short* Qh = Qb + hbase;
  const unsigned short* Kh = Kb + hbase;
  const unsigned short* Vh = Vb + hbase;

  const int qrow = q0 + w*16 + l15;
  const short8 qa0 = *(const short8*)&Qh[(size_t)qrow*HDIM + g*8];
  const short8 qa1 = *(const short8*)&Qh[(size_t)qrow*HDIM + 32 + g*8];

  float mrow[4], lrow[4];
  f32x4 o[4];
  #pragma unroll
  for (int r=0;r<4;++r){ mrow[r] = -1e30f; lrow[r] = 0.f; }
  #pragma unroll
  for (int d=0;d<4;++d) o[d] = (f32x4){0.f,0.f,0.f,0.f};

  const int vk = t>>2;          // staging: V row within tile
  const int vc = (t&3)*16;      // staging: d-col base

  for (int kt=0; kt<32; ++kt){
    __syncthreads();                              // prev PV reads done
    // stage V^T (transpose through registers)
    const unsigned short* vsrc = &Vh[(size_t)(kt*64+vk)*HDIM + vc];
    short8 v0 = *(const short8*)vsrc;
    short8 v1 = *(const short8*)(vsrc+8);
    #pragma unroll
    for (int j=0;j<8;++j){
      Vt[(vc+j)*72   + vk] = (unsigned short)v0[j];
      Vt[(vc+8+j)*72 + vk] = (unsigned short)v1[j];
    }
    // S = Q K^T (K frags direct from global; L1/L2-resident)
    f32x4 sa[4];
    #pragma unroll
    for (int nb=0;nb<4;++nb) sa[nb] = (f32x4){0.f,0.f,0.f,0.f};
    #pragma unroll
    for (int nb=0;nb<4;++nb){
      const unsigned short* krow = &Kh[(size_t)(kt*64 + nb*16 + l15)*HDIM];
      short8 k0v = *(const short8*)&krow[g*8];
      short8 k1v = *(const short8*)&krow[32 + g*8];
      sa[nb] = __builtin_amdgcn_mfma_f32_16x16x32_bf16(qa0, k0v, sa[nb], 0,0,0);
      sa[nb] = __builtin_amdgcn_mfma_f32_16x16x32_bf16(qa1, k1v, sa[nb], 0,0,0);
    }
    // online softmax (rows = (g*4+r); cols across 16 lanes x 4 nb)
    float pmax[4];
    #pragma unroll
    for (int r=0;r<4;++r){
      float mx = fmaxf(fmaxf(sa[0][r], sa[1][r]), fmaxf(sa[2][r], sa[3][r]));
      pmax[r] = mx * 0.125f;
    }
    #pragma unroll
    for (int msk=1; msk<16; msk<<=1){
      #pragma unroll
      for (int r=0;r<4;++r) pmax[r] = fmaxf(pmax[r], __shfl_xor(pmax[r], msk));
    }
    float nm[4], fsc[4], rs[4], p[4][4];
    #pragma unroll
    for (int r=0;r<4;++r){
      nm[r]  = fmaxf(mrow[r], pmax[r]);
      fsc[r] = __expf(mrow[r] - nm[r]);
      rs[r]  = 0.f;
    }
    #pragma unroll
    for (int nb=0;nb<4;++nb)
      #pragma unroll
      for (int r=0;r<4;++r){
        p[nb][r] = __expf(sa[nb][r]*0.125f - nm[r]);
        rs[r] += p[nb][r];
      }
    #pragma unroll
    for (int msk=1; msk<16; msk<<=1){
      #pragma unroll
      for (int r=0;r<4;++r) rs[r] += __shfl_xor(rs[r], msk);
    }
    #pragma unroll
    for (int r=0;r<4;++r){ lrow[r] = lrow[r]*fsc[r] + rs[r]; mrow[r] = nm[r]; }
    #pragma unroll
    for (int d=0;d<4;++d)
      #pragma unroll
      for (int r=0;r<4;++r) o[d][r] *= fsc[r];
    // P (C-layout) -> LDS bf16 row-major (A-layout readable)
    unsigned short* Pw = &Pl[w][0];
    #pragma unroll
    for (int nb=0;nb<4;++nb)
      #pragma unroll
      for (int r=0;r<4;++r)
        Pw[(g*4+r)*72 + nb*16 + l15] = f2bf(p[nb][r]);
    __syncthreads();                              // Vt staged
    // O += P V
    #pragma unroll
    for (int kc=0;kc<2;++kc){
      short8 pa = *(const short8*)&Pw[l15*72 + kc*32 + g*8];
      #pragma unroll
      for (int db=0;db<4;++db){
        short8 vb8 = *(const short8*)&Vt[(db*16+l15)*72 + kc*32 + g*8];
        o[db] = __builtin_amdgcn_mfma_f32_16x16x32_bf16(pa, vb8, o[db], 0,0,0);
      }
    }
  }
  // epilogue: normalize, write ctx fp32 in [B][S][H*64] (= output layout)
  const int b_ = bh>>4, h = bh&15;
  #pragma unroll
  for (int db=0;db<4;++db){
    #pragma unroll
    for (int r=0;r<4;++r){
      const int s = q0 + w*16 + g*4 + r;
      ctx[((size_t)(b_*SEQ + s))*D_MODEL + h*64 + db*16 + l15] = o[db][r] / lrow[r];
    }
  }
}

// ---------------- kernel 5: residual + LayerNorm ----------------
__global__ __launch_bounds__(256) void resid_ln(
  const float* __restrict__ ctx, const float* __restrict__ x,
  const float* __restrict__ gamma, const float* __restrict__ beta,
  float* __restrict__ out)
{
  const int row = blockIdx.x, t = threadIdx.x;
  const size_t base = (size_t)row*D_MODEL;
  float4 c  = ((const float4*)(ctx + base))[t];
  float4 xr = ((const float4*)(x   + base))[t];
  float4 v; v.x=c.x+xr.x; v.y=c.y+xr.y; v.z=c.z+xr.z; v.w=c.w+xr.w;
  float s  = v.x+v.y+v.z+v.w;
  float ss = v.x*v.x+v.y*v.y+v.z*v.z+v.w*v.w;
  #pragma unroll
  for (int m=1;m<64;m<<=1){ s += __shfl_xor(s,m); ss += __shfl_xor(ss,m); }
  __shared__ float red[8];
  const int w = t>>6;
  if ((t&63)==0){ red[w] = s; red[4+w] = ss; }
  __syncthreads();
  s  = red[0]+red[1]+red[2]+red[3];
  ss = red[4]+red[5]+red[6]+red[7];
  const float mean = s*(1.f/D_MODEL);
  const float var  = ss*(1.f/D_MODEL) - mean*mean;
  const float rstd = rsqrtf(var + 1e-3f);
  float4 gv = ((const float4*)gamma)[t], bv = ((const float4*)beta)[t];
  float4 ov;
  ov.x=(v.x-mean)*rstd*gv.x+bv.x; ov.y=(v.y-mean)*rstd*gv.y+bv.y;
  ov.z=(v.z-mean)*rstd*gv.z+bv.z; ov.w=(v.w-mean)*rstd*gv.w+bv.w;
  ((float4*)(out + base))[t] = ov;
}

extern "C" void kernel_launch(void* const* d_in, const int* in_sizes, int n_in,
                              void* d_out, int out_size, void* d_ws, size_t ws_size,
                              hipStream_t stream){
  const float* x     = (const float*)d_in[0];
  const float* Wq    = (const float*)d_in[1];
  const float* bq    = (const float*)d_in[2];
  const float* Wk    = (const float*)d_in[3];
  const float* bk    = (const float*)d_in[4];
  const float* Wv    = (const float*)d_in[5];
  const float* bv    = (const float*)d_in[6];
  const float* gamma = (const float*)d_in[7];
  const float* beta  = (const float*)d_in[8];
  float* out = (float*)d_out;

  char* ws = (char*)d_ws;
  unsigned short* xb  = (unsigned short*)(ws);                    // 8 MB
  unsigned short* wtb = (unsigned short*)(ws + 8388608);          // 6 MB
  unsigned short* qb  = (unsigned short*)(ws + 14680064);         // 8 MB
  unsigned short* kb  = (unsigned short*)(ws + 23068672);         // 8 MB
  unsigned short* vb  = (unsigned short*)(ws + 31457280);         // 8 MB
  float* ctx          = (float*)(ws + 39845888);                  // 16 MB

  hipLaunchKernelGGL(cvt_x,    dim3(ROWS*D_MODEL/1024), dim3(256), 0, stream, x, xb);
  hipLaunchKernelGGL(wtrans,   dim3(32,32,3),           dim3(256), 0, stream, Wq, Wk, Wv, wtb);
  hipLaunchKernelGGL(qkv_gemm, dim3(32,8,3),            dim3(256), 0, stream,
                     xb, wtb, bq, bk, bv, qb, kb, vb);
  hipLaunchKernelGGL(attn_fwd, dim3(SEQ/64, BATCH*NHEADS), dim3(256), 0, stream, qb, kb, vb, ctx);
  hipLaunchKernelGGL(resid_ln, dim3(ROWS),              dim3(256), 0, stream, ctx, x, gamma, beta, out);
}